// Round 10
// baseline (304.117 us; speedup 1.0000x reference)
//
#include <hip/hip_runtime.h>
#include <cstddef>

// Problem constants (fixed by the reference)
constexpr int Bn = 2048;   // batch
constexpr int In = 4096;   // rated items
constexpr int Dn = 512;    // embedding dim

typedef _Float16 f16;
typedef _Float16 f16x8 __attribute__((ext_vector_type(8)));
typedef float    f32x4 __attribute__((ext_vector_type(4)));

// ---------------------------------------------------------------------------
// rs[i] = rated_items[i,:] . att_w[D:2D]  (per-item attention logit).
// ---------------------------------------------------------------------------
__global__ __launch_bounds__(256) void k_rs(const float* __restrict__ rated,
                                            const float* __restrict__ att_w,
                                            float* __restrict__ rs) {
  const int wid  = threadIdx.x >> 6;
  const int lane = threadIdx.x & 63;
  const int i = blockIdx.x * 4 + wid;
  const float* row = rated + (size_t)i * Dn;
  const float* wr  = att_w + Dn;
  float s = 0.f;
  #pragma unroll
  for (int d = 0; d < Dn / 64; ++d)
    s = fmaf(row[lane + d * 64], wr[lane + d * 64], s);
  #pragma unroll
  for (int off = 32; off > 0; off >>= 1) s += __shfl_down(s, off);
  if (lane == 0) rs[i] = s;
}

// ---------------------------------------------------------------------------
// Dense fp16 attention-weight row (verified round 7/8/9):
//   w[b][i] = um!=0 ? exp(rs[i]-m_b)*um[b][i] / S_b : 0,  S_b = SUM exp(rs-m)
// ---------------------------------------------------------------------------
__global__ __launch_bounds__(256) void k_att(const float* __restrict__ um,
                                             const float* __restrict__ rs,
                                             f16* __restrict__ att) {
  __shared__ float t[In];
  __shared__ float red[4];
  const int tid = threadIdx.x;
  const int b = blockIdx.x;
  const float* umrow = um + (size_t)b * In;

  float ua[16];
  float lmax = -INFINITY;
  #pragma unroll
  for (int it = 0; it < 4; ++it) {
    const int i = (it * 256 + tid) * 4;
    const float4 v = *reinterpret_cast<const float4*>(umrow + i);
    ua[it * 4 + 0] = v.x; ua[it * 4 + 1] = v.y;
    ua[it * 4 + 2] = v.z; ua[it * 4 + 3] = v.w;
    #pragma unroll
    for (int j = 0; j < 4; ++j) {
      if (ua[it * 4 + j] != 0.f) {
        const float r = rs[i + j];
        t[i + j] = r;
        lmax = fmaxf(lmax, r);
      } else {
        t[i + j] = -INFINITY;
      }
    }
  }
  #pragma unroll
  for (int off = 32; off > 0; off >>= 1) lmax = fmaxf(lmax, __shfl_down(lmax, off));
  if ((tid & 63) == 0) red[tid >> 6] = lmax;
  __syncthreads();
  const float m = fmaxf(fmaxf(red[0], red[1]), fmaxf(red[2], red[3]));
  __syncthreads();

  float lsum = 0.f;
  #pragma unroll
  for (int it = 0; it < 4; ++it) {
    const int i = (it * 256 + tid) * 4;
    #pragma unroll
    for (int j = 0; j < 4; ++j) {
      float v = 0.f;
      if (ua[it * 4 + j] != 0.f) {
        const float e = __expf(t[i + j] - m);
        lsum += e;                    // denominator: plain exp sum
        v = e * ua[it * 4 + j];
      }
      t[i + j] = v;
    }
  }
  #pragma unroll
  for (int off = 32; off > 0; off >>= 1) lsum += __shfl_down(lsum, off);
  if ((tid & 63) == 0) red[tid >> 6] = lsum;
  __syncthreads();
  const float S = red[0] + red[1] + red[2] + red[3];
  const float inv = (S > 0.f) ? 1.0f / S : 0.0f;

  f16* arow = att + (size_t)b * In;
  #pragma unroll
  for (int it = 0; it < 2; ++it) {
    const int i = (it * 256 + tid) * 8;
    f16x8 h;
    #pragma unroll
    for (int j = 0; j < 8; ++j) h[j] = (f16)(t[i + j] * inv);
    *reinterpret_cast<f16x8*>(arow + i) = h;
  }
}

// ---------------------------------------------------------------------------
// Merged weight-prep: 8 transposes (fp32 [K][N] -> fp16 [N][K]) + 1 cast in
// ONE dispatch (round-9 had 9 small dispatches; launch+tail overhead ~25us).
// ---------------------------------------------------------------------------
struct PrepDesc { const float* src; f16* dst; int K, N, nt, isCast; };
struct PrepPack { PrepDesc d[9]; };

__global__ __launch_bounds__(256) void k_prep(PrepPack pk) {
  __shared__ float tile[32][33];
  int local = blockIdx.x;
  int q = 0;
  while (local >= pk.d[q].nt) { local -= pk.d[q].nt; ++q; }
  const PrepDesc dd = pk.d[q];
  const int tid = threadIdx.x;

  if (dd.isCast) {
    const int i = (local * 256 + tid) * 4;
    const float4 v = *reinterpret_cast<const float4*>(dd.src + i);
    f16* p = dd.dst + i;
    p[0] = (f16)v.x; p[1] = (f16)v.y; p[2] = (f16)v.z; p[3] = (f16)v.w;
    return;
  }
  const int tx = tid & 31;
  const int ty = tid >> 5;
  const int n0 = (local % (dd.N / 32)) * 32;
  const int k0 = (local / (dd.N / 32)) * 32;
  #pragma unroll
  for (int i = 0; i < 4; ++i)
    tile[ty + i * 8][tx] = dd.src[(size_t)(k0 + ty + i * 8) * dd.N + n0 + tx];
  __syncthreads();
  #pragma unroll
  for (int i = 0; i < 4; ++i)
    dd.dst[(size_t)(n0 + ty + i * 8) * dd.K + k0 + tx] = (f16)tile[tx][ty + i * 8];
}

// ---------------------------------------------------------------------------
// Grouped / split-K MFMA GEMM, 128x128 tile, BK=64, 4 waves (2x2 of 64x64).
// Each wave: 4x4 fragments of v_mfma_f32_16x16x32_f16 -> 32 MFMA + 16
// ds_read_b128 per barrier-pair (4x round-9's density; m93 ladder step).
// Fragment lane-maps identical to the HW-verified rounds 4/7/8/9 kernels.
// Split-K writes fp32 partials; k_reduce2 combines (+bias+ReLU+f16).
// ---------------------------------------------------------------------------
struct GemmDesc {
  const f16* A;        // 2048 x K row-major
  const f16* Wt;       // N x K row-major (W transposed)
  const float* bias;   // direct-store path only
  f16* C;              // fp16 out (P==nullptr)
  float* P;            // fp32 partials [S][2048][N]
  int N, K, Kc, ldc, nTilesN, relu;
};

__global__ __launch_bounds__(256) void k_mgemm(GemmDesc dA, GemmDesc dB, int bSplit) {
  const bool second = ((int)blockIdx.x >= bSplit);
  const GemmDesc d = second ? dB : dA;
  const int local = second ? (int)blockIdx.x - bSplit : (int)blockIdx.x;

  const int bm = (local & 15) * 128;           // 16 m-tiles (M=2048)
  const int rest = local >> 4;
  const int bn = (rest % d.nTilesN) * 128;
  const int ks = rest / d.nTilesN;
  const int kBeg = ks * d.Kc;

  __shared__ __align__(16) f16 As[128][72];
  __shared__ __align__(16) f16 Bs[128][72];

  const int tid  = threadIdx.x;
  const int lane = tid & 63;
  const int wave = tid >> 6;
  const int wrow = (wave >> 1) * 64;
  const int wcol = (wave & 1) * 64;
  const int lrow = lane & 15;
  const int koff = (lane >> 4) * 8;

  // staging: thread -> (row tid>>1 of 128, 32-half chunk at (tid&1)*32)
  const int ar = tid >> 1;
  const int ac = (tid & 1) * 32;

  const f16* pa = d.A  + (size_t)(bm + ar) * d.K + kBeg + ac;
  const f16* pb = d.Wt + (size_t)(bn + ar) * d.K + kBeg + ac;

  f16x8 ra0, ra1, ra2, ra3, rb0, rb1, rb2, rb3;
  #define LOADG()                                                   \
    ra0 = *reinterpret_cast<const f16x8*>(pa +  0);                 \
    ra1 = *reinterpret_cast<const f16x8*>(pa +  8);                 \
    ra2 = *reinterpret_cast<const f16x8*>(pa + 16);                 \
    ra3 = *reinterpret_cast<const f16x8*>(pa + 24);                 \
    rb0 = *reinterpret_cast<const f16x8*>(pb +  0);                 \
    rb1 = *reinterpret_cast<const f16x8*>(pb +  8);                 \
    rb2 = *reinterpret_cast<const f16x8*>(pb + 16);                 \
    rb3 = *reinterpret_cast<const f16x8*>(pb + 24);

  f32x4 acc[4][4] = {};

  LOADG();
  for (int k0 = 0; k0 < d.Kc; k0 += 64) {
    *reinterpret_cast<f16x8*>(&As[ar][ac +  0]) = ra0;
    *reinterpret_cast<f16x8*>(&As[ar][ac +  8]) = ra1;
    *reinterpret_cast<f16x8*>(&As[ar][ac + 16]) = ra2;
    *reinterpret_cast<f16x8*>(&As[ar][ac + 24]) = ra3;
    *reinterpret_cast<f16x8*>(&Bs[ar][ac +  0]) = rb0;
    *reinterpret_cast<f16x8*>(&Bs[ar][ac +  8]) = rb1;
    *reinterpret_cast<f16x8*>(&Bs[ar][ac + 16]) = rb2;
    *reinterpret_cast<f16x8*>(&Bs[ar][ac + 24]) = rb3;
    __syncthreads();

    if (k0 + 64 < d.Kc) {          // prefetch next K-tile under the MFMAs
      pa += 64; pb += 64;
      LOADG();
    }

    #pragma unroll
    for (int kss = 0; kss < 2; ++kss) {
      const int kk = kss * 32 + koff;
      f16x8 a[4], b[4];
      #pragma unroll
      for (int m = 0; m < 4; ++m)
        a[m] = *reinterpret_cast<const f16x8*>(&As[wrow + m * 16 + lrow][kk]);
      #pragma unroll
      for (int n = 0; n < 4; ++n)
        b[n] = *reinterpret_cast<const f16x8*>(&Bs[wcol + n * 16 + lrow][kk]);
      #pragma unroll
      for (int m = 0; m < 4; ++m)
        #pragma unroll
        for (int n = 0; n < 4; ++n)
          acc[m][n] = __builtin_amdgcn_mfma_f32_16x16x32_f16(a[m], b[n], acc[m][n], 0, 0, 0);
    }
    __syncthreads();
  }
  #undef LOADG

  // epilogue (C/D map: col=lane&15, row=(lane>>4)*4+reg — HW-verified)
  const int orow = (lane >> 4) * 4;
  if (d.P) {
    float* pp = d.P + (size_t)ks * ((size_t)2048 * d.N);
    #pragma unroll
    for (int mf = 0; mf < 4; ++mf)
      #pragma unroll
      for (int nf = 0; nf < 4; ++nf) {
        const int col = bn + wcol + nf * 16 + lrow;
        #pragma unroll
        for (int rr = 0; rr < 4; ++rr) {
          const int row = bm + wrow + mf * 16 + orow + rr;
          pp[(size_t)row * d.N + col] = acc[mf][nf][rr];
        }
      }
  } else {
    #pragma unroll
    for (int mf = 0; mf < 4; ++mf)
      #pragma unroll
      for (int nf = 0; nf < 4; ++nf) {
        const int col = bn + wcol + nf * 16 + lrow;
        const float bv = d.bias ? d.bias[col] : 0.f;
        #pragma unroll
        for (int rr = 0; rr < 4; ++rr) {
          const int row = bm + wrow + mf * 16 + orow + rr;
          float v = acc[mf][nf][rr] + bv;
          if (d.relu) v = fmaxf(v, 0.f);
          d.C[(size_t)row * d.ldc + col] = (f16)v;
        }
      }
  }
}

// ---------------------------------------------------------------------------
// Sum S fp32 partial planes + bias + ReLU -> fp16; up to two problems per
// dispatch (blockIdx split).  8 elems/thread, fully coalesced.
// ---------------------------------------------------------------------------
struct RedDesc {
  const float* P; int S, MN, N;
  const float* bias; int relu; f16* C; int ldc;
};

__global__ __launch_bounds__(256) void k_reduce2(RedDesc a, RedDesc b, int bSplit) {
  const bool second = ((int)blockIdx.x >= bSplit);
  const RedDesc d = second ? b : a;
  const int local = second ? (int)blockIdx.x - bSplit : (int)blockIdx.x;
  const int idx = (local * 256 + threadIdx.x) * 8;

  float v[8];
  {
    const float4 a0 = *reinterpret_cast<const float4*>(d.P + idx);
    const float4 a1 = *reinterpret_cast<const float4*>(d.P + idx + 4);
    v[0] = a0.x; v[1] = a0.y; v[2] = a0.z; v[3] = a0.w;
    v[4] = a1.x; v[5] = a1.y; v[6] = a1.z; v[7] = a1.w;
  }
  for (int s = 1; s < d.S; ++s) {
    const float* ps = d.P + (size_t)s * d.MN + idx;
    const float4 b0 = *reinterpret_cast<const float4*>(ps);
    const float4 b1 = *reinterpret_cast<const float4*>(ps + 4);
    v[0] += b0.x; v[1] += b0.y; v[2] += b0.z; v[3] += b0.w;
    v[4] += b1.x; v[5] += b1.y; v[6] += b1.z; v[7] += b1.w;
  }
  const int row = idx / d.N;
  const int col = idx % d.N;
  f16x8 h;
  #pragma unroll
  for (int j = 0; j < 8; ++j) {
    float x = v[j] + (d.bias ? d.bias[col + j] : 0.f);
    if (d.relu) x = fmaxf(x, 0.f);
    h[j] = (f16)x;
  }
  *reinterpret_cast<f16x8*>(d.C + (size_t)row * d.ldc + col) = h;
}

// ---------------------------------------------------------------------------
// Fused merge-layer-3 + final projection (replaces MFMA m3 + reduce + final):
//   x = relu(h2 @ mw3 + mb3);  out = x @ mw4 + mb4
// 4 rows per block; thread j owns output column j (t_mw3 row j contiguous).
// mw3 is 256KB -> L2-resident; VALU cost ~540 MFLOP total.
// ---------------------------------------------------------------------------
__global__ __launch_bounds__(256) void k_tail(const f16* __restrict__ h2,
                                              const f16* __restrict__ t_mw3,
                                              const float* __restrict__ mb3,
                                              const float* __restrict__ mw4,
                                              const float* __restrict__ mb4,
                                              float* __restrict__ out) {
  __shared__ f16 rows[4][512];
  __shared__ float red[4][4];
  const int tid = threadIdx.x;
  const int r0 = blockIdx.x * 4;

  // stage 4 input rows (each thread one f16x8)
  *reinterpret_cast<f16x8*>(&rows[tid >> 6][(tid & 63) * 8]) =
      *reinterpret_cast<const f16x8*>(&h2[(size_t)(r0 + (tid >> 6)) * 512 + (tid & 63) * 8]);
  __syncthreads();

  const int j = tid;                 // output column 0..255
  float acc[4] = {};
  for (int k = 0; k < 512; k += 8) {
    const f16x8 w = *reinterpret_cast<const f16x8*>(&t_mw3[(size_t)j * 512 + k]);
    #pragma unroll
    for (int e = 0; e < 8; ++e) {
      const float wf = (float)w[e];
      #pragma unroll
      for (int r = 0; r < 4; ++r)
        acc[r] = fmaf(wf, (float)rows[r][k + e], acc[r]);
    }
  }
  const float b3 = mb3[j];
  const float m4 = mw4[j];
  const int lane = tid & 63;
  const int wid  = tid >> 6;
  #pragma unroll
  for (int r = 0; r < 4; ++r) {
    float v = fmaxf(acc[r] + b3, 0.f) * m4;
    #pragma unroll
    for (int off = 32; off > 0; off >>= 1) v += __shfl_down(v, off);
    if (lane == 0) red[r][wid] = v;
  }
  __syncthreads();
  if (tid < 4)
    out[r0 + tid] = red[tid][0] + red[tid][1] + red[tid][2] + red[tid][3] + mb4[0];
}

// ---------------------------------------------------------------------------
extern "C" void kernel_launch(void* const* d_in, const int* in_sizes, int n_in,
                              void* d_out, int out_size, void* d_ws, size_t ws_size,
                              hipStream_t stream) {
  const float* cand  = (const float*)d_in[0];
  const float* rated = (const float*)d_in[1];
  const float* um    = (const float*)d_in[2];
  const float* att_w = (const float*)d_in[3];
  const float* iw1 = (const float*)d_in[5];
  const float* ib1 = (const float*)d_in[6];
  const float* iw2 = (const float*)d_in[7];
  const float* ib2 = (const float*)d_in[8];
  const float* uw1 = (const float*)d_in[9];
  const float* ub1 = (const float*)d_in[10];
  const float* uw2 = (const float*)d_in[11];
  const float* ub2 = (const float*)d_in[12];
  const float* mw1 = (const float*)d_in[13];
  const float* mb1 = (const float*)d_in[14];
  const float* mw2 = (const float*)d_in[15];
  const float* mb2 = (const float*)d_in[16];
  const float* mw3 = (const float*)d_in[17];
  const float* mb3 = (const float*)d_in[18];
  const float* mw4 = (const float*)d_in[19];
  const float* mb4 = (const float*)d_in[20];
  float* out = (float*)d_out;

  // ---- workspace layout (fp16 element units); ~73 MB ----
  f16*   hws = (f16*)d_ws;
  float* rs  = (float*)d_ws;            // 4096 fp32 = 8192 half-slots
  size_t off = 8192;
  auto take = [&](size_t n) { f16* p = hws + off; off += n; return p; };
  f16* t_iw1   = take(512 * 1024);
  f16* t_iw2   = take(1024 * 512);
  f16* t_uw1   = take(512 * 2048);
  f16* t_uw2   = take(2048 * 1024);
  f16* t_mw1   = take(1536 * 1024);
  f16* t_mw2   = take(1024 * 512);
  f16* t_mw3   = take(512 * 256);
  f16* t_rated = take(512 * 4096);
  f16* cand_h  = take(2048 * 512);
  f16* uf_h    = take(2048 * 512);
  f16* big     = take(2048 * 2048);     // att_d head / h_u1 / h_m1
  f16* Xc      = take(2048 * 1536);     // att_d mid / concat buffer
  f16* spare   = take(2048 * 512);      // att_d tail
  f16* h_i1b   = take(2048 * 1024);     // dedicated (concurrent with att_d use)
  float* PA    = (float*)take(4 * 2048 * 512 * 2);   // 16 MB fp32 partials
  float* PB    = (float*)take(2 * 2048 * 1024 * 2);  // 16 MB fp32 partials
  (void)spare;
  f16* att_d = big;                     // 2048x4096 spans [big|Xc|spare]
  f16* h_u1 = big;                      // 2048x2048 (att_d dead after G1)
  f16* h_m1 = big;                      // 2048x1024 (h_u1 dead after G3/R3)
  f16* h_m2 = uf_h;                     // 2048x512  (uf dead after G2)

  dim3 blk(256);

  // 0. attention logits, merged weight prep, dense attention matrix
  k_rs<<<dim3(In / 4), blk, 0, stream>>>(rated, att_w, rs);
  PrepPack pk = {{
      { rated, t_rated, 4096,  512, (512/32)*(4096/32), 0 },
      { iw1,   t_iw1,    512, 1024, (1024/32)*(512/32), 0 },
      { iw2,   t_iw2,   1024,  512, (512/32)*(1024/32), 0 },
      { uw1,   t_uw1,    512, 2048, (2048/32)*(512/32), 0 },
      { uw2,   t_uw2,   2048, 1024, (1024/32)*(2048/32), 0 },
      { mw1,   t_mw1,   1536, 1024, (1024/32)*(1536/32), 0 },
      { mw2,   t_mw2,   1024,  512, (512/32)*(1024/32), 0 },
      { mw3,   t_mw3,    512,  256, (256/32)*(512/32), 0 },
      { cand,  cand_h,     0,    0, (Bn * Dn) / 1024, 1 },
  }};
  int prepGrid = 0;
  for (int q = 0; q < 9; ++q) prepGrid += pk.d[q].nt;
  k_prep<<<dim3(prepGrid), blk, 0, stream>>>(pk);
  k_att<<<dim3(Bn), blk, 0, stream>>>(um, rs, att_d);

  // GEMM descriptors (128x128 tiles; M-tiles = 16)
  GemmDesc dUF = { att_d,  t_rated, nullptr, nullptr, PA, 512, 4096, 1024, 512, 4, 0 };
  GemmDesc dI1 = { cand_h, t_iw1,   nullptr, nullptr, PB, 1024, 512, 256, 1024, 8, 1 };
  GemmDesc dI2 = { h_i1b,  t_iw2,   nullptr, nullptr, PA, 512, 1024, 256, 1536, 4, 1 };
  GemmDesc dU1 = { uf_h,   t_uw1,   ub1, h_u1, nullptr, 2048, 512, 512, 2048, 16, 1 };
  GemmDesc dU2 = { h_u1,   t_uw2,   nullptr, nullptr, PA, 1024, 2048, 1024, 1536, 8, 1 };
  GemmDesc dM1 = { Xc,     t_mw1,   nullptr, nullptr, PA, 1024, 1536, 768, 1024, 8, 1 };
  GemmDesc dM2 = { h_m1,   t_mw2,   nullptr, nullptr, PA, 512, 1024, 256, 512, 4, 1 };

  RedDesc rUF = { PA, 4, 2048 * 512,  512,  nullptr, 0, uf_h,  512 };
  RedDesc rI1 = { PB, 2, 2048 * 1024, 1024, ib1, 1, h_i1b, 1024 };
  RedDesc rI2 = { PA, 4, 2048 * 512,  512,  ib2, 1, Xc,       1536 };
  RedDesc rU2 = { PA, 2, 2048 * 1024, 1024, ub2, 1, Xc + 512, 1536 };
  RedDesc rM1 = { PA, 2, 2048 * 1024, 1024, mb1, 1, h_m1, 1024 };
  RedDesc rM2 = { PA, 4, 2048 * 512,  512,  mb2, 1, h_m2, 512 };

  // G1: user_feat (S=4, 256wg) + item layer 1 (S=2, 256wg)
  k_mgemm<<<dim3(512), blk, 0, stream>>>(dUF, dI1, 256);
  k_reduce2<<<dim3(512 + 1024), blk, 0, stream>>>(rUF, rI1, 512);

  // G2: item layer 2 (S=4, 256wg) + user layer 1 (direct, 256wg)
  k_mgemm<<<dim3(512), blk, 0, stream>>>(dI2, dU1, 256);
  k_reduce2<<<dim3(512), blk, 0, stream>>>(rI2, rI2, 512);

  // G3: user layer 2 (S=2, 256wg)
  k_mgemm<<<dim3(256), blk, 0, stream>>>(dU2, dU2, 256);
  k_reduce2<<<dim3(1024), blk, 0, stream>>>(rU2, rU2, 1024);

  // G4: merge layer 1 (S=2, 256wg)
  k_mgemm<<<dim3(256), blk, 0, stream>>>(dM1, dM1, 256);
  k_reduce2<<<dim3(1024), blk, 0, stream>>>(rM1, rM1, 1024);

  // G5: merge layer 2 (S=4, 256wg)
  k_mgemm<<<dim3(256), blk, 0, stream>>>(dM2, dM2, 256);
  k_reduce2<<<dim3(512), blk, 0, stream>>>(rM2, rM2, 512);

  // fused merge layer 3 + final projection
  k_tail<<<dim3(Bn / 4), blk, 0, stream>>>(h_m2, t_mw3, mb3, mw4, mb4, out);
}

// Round 12
// 300.656 us; speedup vs baseline: 1.0115x; 1.0115x over previous
//
#include <hip/hip_runtime.h>
#include <cstddef>

// Problem constants (fixed by the reference)
constexpr int Bn = 2048;   // batch
constexpr int In = 4096;   // rated items
constexpr int Dn = 512;    // embedding dim

typedef _Float16 f16;
typedef _Float16 f16x8 __attribute__((ext_vector_type(8)));
typedef float    f32x4 __attribute__((ext_vector_type(4)));

// Async global->LDS, 16B per lane. LDS dst must be WAVE-UNIFORM base;
// HW writes lane i at base + i*16 (m104). Size must be a literal.
__device__ __forceinline__ void gld16(const f16* g, f16* l) {
  __builtin_amdgcn_global_load_lds(
      (const __attribute__((address_space(1))) void*)g,
      (__attribute__((address_space(3))) void*)l, 16, 0, 0);
}

// ---------------------------------------------------------------------------
// rs[i] = rated_items[i,:] . att_w[D:2D]  (per-item attention logit).
// ---------------------------------------------------------------------------
__global__ __launch_bounds__(256) void k_rs(const float* __restrict__ rated,
                                            const float* __restrict__ att_w,
                                            float* __restrict__ rs) {
  const int wid  = threadIdx.x >> 6;
  const int lane = threadIdx.x & 63;
  const int i = blockIdx.x * 4 + wid;
  const float* row = rated + (size_t)i * Dn;
  const float* wr  = att_w + Dn;
  float s = 0.f;
  #pragma unroll
  for (int d = 0; d < Dn / 64; ++d)
    s = fmaf(row[lane + d * 64], wr[lane + d * 64], s);
  #pragma unroll
  for (int off = 32; off > 0; off >>= 1) s += __shfl_down(s, off);
  if (lane == 0) rs[i] = s;
}

// ---------------------------------------------------------------------------
// Merged attention-densify + ALL weight prep in ONE dispatch.
// Blocks [0, Bn): att rows (verified r7-r10 math: S = plain exp-sum).
// Blocks [Bn, ...): 8 fp32->fp16 transposes + candidate cast.
// ---------------------------------------------------------------------------
struct PrepDesc { const float* src; f16* dst; int K, N, nt, isCast; };
struct PrepPack { PrepDesc d[9]; };

__global__ __launch_bounds__(256) void k_attprep(const float* __restrict__ um,
                                                 const float* __restrict__ rs,
                                                 f16* __restrict__ att,
                                                 PrepPack pk) {
  __shared__ float smem[4100];        // att: t[4096]+red[4]; prep: tile[32][33]
  const int tid = threadIdx.x;

  if ((int)blockIdx.x >= Bn) {        // ---- prep path ----
    int local = blockIdx.x - Bn;
    int q = 0;
    while (local >= pk.d[q].nt) { local -= pk.d[q].nt; ++q; }
    const PrepDesc dd = pk.d[q];
    if (dd.isCast) {
      const int i = (local * 256 + tid) * 4;
      const float4 v = *reinterpret_cast<const float4*>(dd.src + i);
      f16* p = dd.dst + i;
      p[0] = (f16)v.x; p[1] = (f16)v.y; p[2] = (f16)v.z; p[3] = (f16)v.w;
      return;
    }
    float (*tile)[33] = reinterpret_cast<float (*)[33]>(smem);
    const int tx = tid & 31;
    const int ty = tid >> 5;
    const int n0 = (local % (dd.N / 32)) * 32;
    const int k0 = (local / (dd.N / 32)) * 32;
    #pragma unroll
    for (int i = 0; i < 4; ++i)
      tile[ty + i * 8][tx] = dd.src[(size_t)(k0 + ty + i * 8) * dd.N + n0 + tx];
    __syncthreads();
    #pragma unroll
    for (int i = 0; i < 4; ++i)
      dd.dst[(size_t)(n0 + ty + i * 8) * dd.K + k0 + tx] = (f16)tile[tx][ty + i * 8];
    return;
  }

  // ---- attention path (math verified rounds 7-10) ----
  float* t = smem;
  float* red = smem + 4096;
  const int b = blockIdx.x;
  const float* umrow = um + (size_t)b * In;

  float ua[16];
  float lmax = -INFINITY;
  #pragma unroll
  for (int it = 0; it < 4; ++it) {
    const int i = (it * 256 + tid) * 4;
    const float4 v = *reinterpret_cast<const float4*>(umrow + i);
    ua[it * 4 + 0] = v.x; ua[it * 4 + 1] = v.y;
    ua[it * 4 + 2] = v.z; ua[it * 4 + 3] = v.w;
    #pragma unroll
    for (int j = 0; j < 4; ++j) {
      if (ua[it * 4 + j] != 0.f) {
        const float r = rs[i + j];
        t[i + j] = r;
        lmax = fmaxf(lmax, r);
      } else {
        t[i + j] = -INFINITY;
      }
    }
  }
  #pragma unroll
  for (int off = 32; off > 0; off >>= 1) lmax = fmaxf(lmax, __shfl_down(lmax, off));
  if ((tid & 63) == 0) red[tid >> 6] = lmax;
  __syncthreads();
  const float m = fmaxf(fmaxf(red[0], red[1]), fmaxf(red[2], red[3]));
  __syncthreads();

  float lsum = 0.f;
  #pragma unroll
  for (int it = 0; it < 4; ++it) {
    const int i = (it * 256 + tid) * 4;
    #pragma unroll
    for (int j = 0; j < 4; ++j) {
      float v = 0.f;
      if (ua[it * 4 + j] != 0.f) {
        const float e = __expf(t[i + j] - m);
        lsum += e;                    // denominator: plain exp sum
        v = e * ua[it * 4 + j];
      }
      t[i + j] = v;
    }
  }
  #pragma unroll
  for (int off = 32; off > 0; off >>= 1) lsum += __shfl_down(lsum, off);
  if ((tid & 63) == 0) red[tid >> 6] = lsum;
  __syncthreads();
  const float S = red[0] + red[1] + red[2] + red[3];
  const float inv = (S > 0.f) ? 1.0f / S : 0.0f;

  f16* arow = att + (size_t)b * In;
  #pragma unroll
  for (int it = 0; it < 2; ++it) {
    const int i = (it * 256 + tid) * 8;
    f16x8 h;
    #pragma unroll
    for (int j = 0; j < 8; ++j) h[j] = (f16)(t[i + j] * inv);
    *reinterpret_cast<f16x8*>(arow + i) = h;
  }
}

// ---------------------------------------------------------------------------
// Grouped MFMA GEMM, 64x64 tile, BK=64, 4 waves (2x2 of 32x32), NO split-K.
// Staging via global_load_lds width=16 into LINEAR (unpadded) LDS — the m97
// mechanism (Common-mistake #1: compiler never auto-emits it; +67% measured).
// Chunk map: chunk c (= wave*2 + j) covers tile rows [c*8, c*8+8); lane l
// supplies row c*8 + l/8, halfs (l&7)*8..+8; LDS dst = base + c*1024 B
// (wave-uniform) so HW's base+lane*16 lands each lane exactly row-major.
// Bank conflicts of the unpadded layout are accepted: T2-swizzle is
// measured-null on 2-phase loops (m228d) and m97 hit 874 TF with them.
// Fragment lane-maps identical to HW-verified rounds 4/7/8/9/10 kernels.
// ---------------------------------------------------------------------------
struct GemmDesc {
  const f16* A;        // 2048 x K row-major
  const f16* Wt;       // N x K row-major (W transposed)
  const float* bias;
  f16* C;              // fp16 out
  int K, ldc, relu;
};

__global__ __launch_bounds__(256, 2) void k_mgemm(GemmDesc dA, GemmDesc dB, int bSplit) {
  __shared__ __align__(16) f16 As[64 * 64];
  __shared__ __align__(16) f16 Bs[64 * 64];

  const bool second = ((int)blockIdx.x >= bSplit);
  const GemmDesc d = second ? dB : dA;
  const int local = second ? (int)blockIdx.x - bSplit : (int)blockIdx.x;

  const int bm = (local & 31) * 64;            // 32 m-tiles (M=2048)
  const int bn = (local >> 5) * 64;

  const int tid  = threadIdx.x;
  const int lane = tid & 63;
  const int wave = tid >> 6;
  const int wrow = (wave >> 1) * 32;
  const int wcol = (wave & 1) * 32;
  const int lrow = lane & 15;
  const int koff = (lane >> 4) * 8;

  // staging chunks: this wave owns chunks c0, c0+1 (8 rows each)
  const int c0   = wave * 2;
  const int rgrp = lane >> 3;                  // 0..7 (row within chunk)
  const int colh = (lane & 7) * 8;             // halfs 0,8,..,56

  const f16* gA0 = d.A  + (size_t)(bm + c0 * 8 + rgrp) * d.K + colh;
  const f16* gA1 = d.A  + (size_t)(bm + c0 * 8 + 8 + rgrp) * d.K + colh;
  const f16* gB0 = d.Wt + (size_t)(bn + c0 * 8 + rgrp) * d.K + colh;
  const f16* gB1 = d.Wt + (size_t)(bn + c0 * 8 + 8 + rgrp) * d.K + colh;
  f16* lA0 = &As[(c0 + 0) * 512];              // wave-uniform LDS bases
  f16* lA1 = &As[(c0 + 1) * 512];
  f16* lB0 = &Bs[(c0 + 0) * 512];
  f16* lB1 = &Bs[(c0 + 1) * 512];

  f32x4 acc[2][2] = {};

  for (int k0 = 0; k0 < d.K; k0 += 64) {
    gld16(gA0 + k0, lA0);
    gld16(gA1 + k0, lA1);
    gld16(gB0 + k0, lB0);
    gld16(gB1 + k0, lB1);
    __syncthreads();                 // drains vmcnt -> tiles resident

    #pragma unroll
    for (int kss = 0; kss < 2; ++kss) {
      const int kk = kss * 32 + koff;
      const f16x8 a0 = *reinterpret_cast<const f16x8*>(&As[(wrow +  0 + lrow) * 64 + kk]);
      const f16x8 a1 = *reinterpret_cast<const f16x8*>(&As[(wrow + 16 + lrow) * 64 + kk]);
      const f16x8 b0 = *reinterpret_cast<const f16x8*>(&Bs[(wcol +  0 + lrow) * 64 + kk]);
      const f16x8 b1 = *reinterpret_cast<const f16x8*>(&Bs[(wcol + 16 + lrow) * 64 + kk]);

      acc[0][0] = __builtin_amdgcn_mfma_f32_16x16x32_f16(a0, b0, acc[0][0], 0, 0, 0);
      acc[0][1] = __builtin_amdgcn_mfma_f32_16x16x32_f16(a0, b1, acc[0][1], 0, 0, 0);
      acc[1][0] = __builtin_amdgcn_mfma_f32_16x16x32_f16(a1, b0, acc[1][0], 0, 0, 0);
      acc[1][1] = __builtin_amdgcn_mfma_f32_16x16x32_f16(a1, b1, acc[1][1], 0, 0, 0);
    }
    __syncthreads();                 // protect LDS before next stage
  }

  // epilogue: bias + ReLU + fp16 store (C/D map: col=lane&15, row=(lane>>4)*4+reg)
  const int orow = (lane >> 4) * 4;
  #pragma unroll
  for (int mf = 0; mf < 2; ++mf)
    #pragma unroll
    for (int nf = 0; nf < 2; ++nf) {
      const int col = bn + wcol + nf * 16 + lrow;
      const float bv = d.bias ? d.bias[col] : 0.f;
      #pragma unroll
      for (int rr = 0; rr < 4; ++rr) {
        const int row = bm + wrow + mf * 16 + orow + rr;
        float v = acc[mf][nf][rr] + bv;
        if (d.relu) v = fmaxf(v, 0.f);
        d.C[(size_t)row * d.ldc + col] = (f16)v;
      }
    }
}

// ---------------------------------------------------------------------------
// Fused merge-layer-3 + final projection (verified round 10):
//   x = relu(h2 @ mw3 + mb3);  out = x @ mw4 + mb4
// ---------------------------------------------------------------------------
__global__ __launch_bounds__(256) void k_tail(const f16* __restrict__ h2,
                                              const f16* __restrict__ t_mw3,
                                              const float* __restrict__ mb3,
                                              const float* __restrict__ mw4,
                                              const float* __restrict__ mb4,
                                              float* __restrict__ out) {
  __shared__ f16 rows[4][512];
  __shared__ float red[4][4];
  const int tid = threadIdx.x;
  const int r0 = blockIdx.x * 4;

  *reinterpret_cast<f16x8*>(&rows[tid >> 6][(tid & 63) * 8]) =
      *reinterpret_cast<const f16x8*>(&h2[(size_t)(r0 + (tid >> 6)) * 512 + (tid & 63) * 8]);
  __syncthreads();

  const int j = tid;                 // output column 0..255
  float acc[4] = {};
  for (int k = 0; k < 512; k += 8) {
    const f16x8 w = *reinterpret_cast<const f16x8*>(&t_mw3[(size_t)j * 512 + k]);
    #pragma unroll
    for (int e = 0; e < 8; ++e) {
      const float wf = (float)w[e];
      #pragma unroll
      for (int r = 0; r < 4; ++r)
        acc[r] = fmaf(wf, (float)rows[r][k + e], acc[r]);
    }
  }
  const float b3 = mb3[j];
  const float m4 = mw4[j];
  const int lane = tid & 63;
  const int wid  = tid >> 6;
  #pragma unroll
  for (int r = 0; r < 4; ++r) {
    float v = fmaxf(acc[r] + b3, 0.f) * m4;
    #pragma unroll
    for (int off = 32; off > 0; off >>= 1) v += __shfl_down(v, off);
    if (lane == 0) red[r][wid] = v;
  }
  __syncthreads();
  if (tid < 4)
    out[r0 + tid] = red[tid][0] + red[tid][1] + red[tid][2] + red[tid][3] + mb4[0];
}

// ---------------------------------------------------------------------------
extern "C" void kernel_launch(void* const* d_in, const int* in_sizes, int n_in,
                              void* d_out, int out_size, void* d_ws, size_t ws_size,
                              hipStream_t stream) {
  const float* cand  = (const float*)d_in[0];
  const float* rated = (const float*)d_in[1];
  const float* um    = (const float*)d_in[2];
  const float* att_w = (const float*)d_in[3];
  const float* iw1 = (const float*)d_in[5];
  const float* ib1 = (const float*)d_in[6];
  const float* iw2 = (const float*)d_in[7];
  const float* ib2 = (const float*)d_in[8];
  const float* uw1 = (const float*)d_in[9];
  const float* ub1 = (const float*)d_in[10];
  const float* uw2 = (const float*)d_in[11];
  const float* ub2 = (const float*)d_in[12];
  const float* mw1 = (const float*)d_in[13];
  const float* mb1 = (const float*)d_in[14];
  const float* mw2 = (const float*)d_in[15];
  const float* mb2 = (const float*)d_in[16];
  const float* mw3 = (const float*)d_in[17];
  const float* mb3 = (const float*)d_in[18];
  const float* mw4 = (const float*)d_in[19];
  const float* mb4 = (const float*)d_in[20];
  float* out = (float*)d_out;

  // ---- workspace layout (fp16 element units); ~49 MB ----
  f16*   hws = (f16*)d_ws;
  float* rs  = (float*)d_ws;            // 4096 fp32 = 8192 half-slots
  size_t off = 8192;
  auto take = [&](size_t n) { f16* p = hws + off; off += n; return p; };
  f16* t_iw1   = take(512 * 1024);
  f16* t_iw2   = take(1024 * 512);
  f16* t_uw1   = take(512 * 2048);
  f16* t_uw2   = take(2048 * 1024);
  f16* t_mw1   = take(1536 * 1024);
  f16* t_mw2   = take(1024 * 512);
  f16* t_mw3   = take(512 * 256);
  f16* t_rated = take(512 * 4096);
  f16* cand_h  = take(2048 * 512);
  f16* uf_h    = take(2048 * 512);
  f16* att_d   = take(2048 * 4096);     // 16 MB; h_u1 aliases after G1
  f16* h_i1    = take(2048 * 1024);     // h_m1 aliases after G2
  f16* Xc      = take(2048 * 1536);     // concat [item_emb | user_emb]
  f16* h_u1 = att_d;                    // 2048x2048 (att_d dead after G1)
  f16* h_m1 = h_i1;                     // 2048x1024 (h_i1 dead after G2)
  f16* h_m2 = uf_h;                     // 2048x512  (uf_h dead after G2)

  dim3 blk(256);

  // 1. attention logits
  k_rs<<<dim3(In / 4), blk, 0, stream>>>(rated, att_w, rs);

  // 2. merged: dense attention matrix + all weight transposes + cand cast
  PrepPack pk = {{
      { rated, t_rated, 4096,  512, (512/32)*(4096/32), 0 },
      { iw1,   t_iw1,    512, 1024, (1024/32)*(512/32), 0 },
      { iw2,   t_iw2,   1024,  512, (512/32)*(1024/32), 0 },
      { uw1,   t_uw1,    512, 2048, (2048/32)*(512/32), 0 },
      { uw2,   t_uw2,   2048, 1024, (1024/32)*(2048/32), 0 },
      { mw1,   t_mw1,   1536, 1024, (1024/32)*(1536/32), 0 },
      { mw2,   t_mw2,   1024,  512, (512/32)*(1024/32), 0 },
      { mw3,   t_mw3,    512,  256, (256/32)*(512/32), 0 },
      { cand,  cand_h,     0,    0, (Bn * Dn) / 1024, 1 },
  }};
  int prepGrid = 0;
  for (int q = 0; q < 9; ++q) prepGrid += pk.d[q].nt;
  k_attprep<<<dim3(Bn + prepGrid), blk, 0, stream>>>(um, rs, att_d, pk);

  // GEMM descriptors (64x64 tiles, grid = 32 * N/64 per problem)
  GemmDesc dUF = { att_d,  t_rated, nullptr, uf_h,     4096,  512, 0 };
  GemmDesc dI1 = { cand_h, t_iw1,   ib1,     h_i1,      512, 1024, 1 };
  GemmDesc dU1 = { uf_h,   t_uw1,   ub1,     h_u1,      512, 2048, 1 };
  GemmDesc dI2 = { h_i1,   t_iw2,   ib2,     Xc,       1024, 1536, 1 };
  GemmDesc dU2 = { h_u1,   t_uw2,   ub2,     Xc + 512, 2048, 1536, 1 };
  GemmDesc dM1 = { Xc,     t_mw1,   mb1,     h_m1,     1536, 1024, 1 };
  GemmDesc dM2 = { h_m1,   t_mw2,   mb2,     h_m2,     1024,  512, 1 };

  // G1: user_feat (256 wg) + item layer 1 (512 wg) = 768 wg, 3 blocks/CU
  k_mgemm<<<dim3(768), blk, 0, stream>>>(dUF, dI1, 256);
  // G2: user layer 1 (1024 wg) + item layer 2 (256 wg) = 1280 wg
  k_mgemm<<<dim3(1280), blk, 0, stream>>>(dU1, dI2, 1024);
  // G3: user layer 2 (512 wg)
  k_mgemm<<<dim3(512), blk, 0, stream>>>(dU2, dU2, 512);
  // G4: merge layer 1 (512 wg)
  k_mgemm<<<dim3(512), blk, 0, stream>>>(dM1, dM1, 512);
  // G5: merge layer 2 (256 wg)
  k_mgemm<<<dim3(256), blk, 0, stream>>>(dM2, dM2, 256);

  // fused merge layer 3 + final projection
  k_tail<<<dim3(Bn / 4), blk, 0, stream>>>(h_m2, t_mw3, mb3, mw4, mb4, out);
}

// Round 13
// 272.760 us; speedup vs baseline: 1.1150x; 1.1023x over previous
//
#include <hip/hip_runtime.h>
#include <cstddef>

// Problem constants (fixed by the reference)
constexpr int Bn = 2048;   // batch
constexpr int In = 4096;   // rated items
constexpr int Dn = 512;    // embedding dim

typedef _Float16 f16;
typedef _Float16 f16x8 __attribute__((ext_vector_type(8)));
typedef float    f32x4 __attribute__((ext_vector_type(4)));

// Async global->LDS, 16B/lane. LDS dst is WAVE-UNIFORM base; HW writes lane i
// at base + i*16 (m104). Global SOURCE is per-lane (m173) -> swizzle there.
__device__ __forceinline__ void gld16(const f16* g, f16* l) {
  __builtin_amdgcn_global_load_lds(
      (const __attribute__((address_space(1))) void*)g,
      (__attribute__((address_space(3))) void*)l, 16, 0, 0);
}

// ---------------------------------------------------------------------------
// rs[i] = rated_items[i,:] . att_w[D:2D]  (per-item attention logit).
// ---------------------------------------------------------------------------
__global__ __launch_bounds__(256) void k_rs(const float* __restrict__ rated,
                                            const float* __restrict__ att_w,
                                            float* __restrict__ rs) {
  const int wid  = threadIdx.x >> 6;
  const int lane = threadIdx.x & 63;
  const int i = blockIdx.x * 4 + wid;
  const float* row = rated + (size_t)i * Dn;
  const float* wr  = att_w + Dn;
  float s = 0.f;
  #pragma unroll
  for (int d = 0; d < Dn / 64; ++d)
    s = fmaf(row[lane + d * 64], wr[lane + d * 64], s);
  #pragma unroll
  for (int off = 32; off > 0; off >>= 1) s += __shfl_down(s, off);
  if (lane == 0) rs[i] = s;
}

// ---------------------------------------------------------------------------
// Merged attention-densify + ALL weight prep in ONE dispatch (verified r12).
// ---------------------------------------------------------------------------
struct PrepDesc { const float* src; f16* dst; int K, N, nt, isCast; };
struct PrepPack { PrepDesc d[9]; };

__global__ __launch_bounds__(256) void k_attprep(const float* __restrict__ um,
                                                 const float* __restrict__ rs,
                                                 f16* __restrict__ att,
                                                 PrepPack pk) {
  __shared__ float smem[4100];
  const int tid = threadIdx.x;

  if ((int)blockIdx.x >= Bn) {        // ---- prep path ----
    int local = blockIdx.x - Bn;
    int q = 0;
    while (local >= pk.d[q].nt) { local -= pk.d[q].nt; ++q; }
    const PrepDesc dd = pk.d[q];
    if (dd.isCast) {
      const int i = (local * 256 + tid) * 4;
      const float4 v = *reinterpret_cast<const float4*>(dd.src + i);
      f16* p = dd.dst + i;
      p[0] = (f16)v.x; p[1] = (f16)v.y; p[2] = (f16)v.z; p[3] = (f16)v.w;
      return;
    }
    float (*tile)[33] = reinterpret_cast<float (*)[33]>(smem);
    const int tx = tid & 31;
    const int ty = tid >> 5;
    const int n0 = (local % (dd.N / 32)) * 32;
    const int k0 = (local / (dd.N / 32)) * 32;
    #pragma unroll
    for (int i = 0; i < 4; ++i)
      tile[ty + i * 8][tx] = dd.src[(size_t)(k0 + ty + i * 8) * dd.N + n0 + tx];
    __syncthreads();
    #pragma unroll
    for (int i = 0; i < 4; ++i)
      dd.dst[(size_t)(n0 + ty + i * 8) * dd.K + k0 + tx] = (f16)tile[tx][ty + i * 8];
    return;
  }

  // ---- attention path (math verified rounds 7-12) ----
  float* t = smem;
  float* red = smem + 4096;
  const int b = blockIdx.x;
  const float* umrow = um + (size_t)b * In;

  float ua[16];
  float lmax = -INFINITY;
  #pragma unroll
  for (int it = 0; it < 4; ++it) {
    const int i = (it * 256 + tid) * 4;
    const float4 v = *reinterpret_cast<const float4*>(umrow + i);
    ua[it * 4 + 0] = v.x; ua[it * 4 + 1] = v.y;
    ua[it * 4 + 2] = v.z; ua[it * 4 + 3] = v.w;
    #pragma unroll
    for (int j = 0; j < 4; ++j) {
      if (ua[it * 4 + j] != 0.f) {
        const float r = rs[i + j];
        t[i + j] = r;
        lmax = fmaxf(lmax, r);
      } else {
        t[i + j] = -INFINITY;
      }
    }
  }
  #pragma unroll
  for (int off = 32; off > 0; off >>= 1) lmax = fmaxf(lmax, __shfl_down(lmax, off));
  if ((tid & 63) == 0) red[tid >> 6] = lmax;
  __syncthreads();
  const float m = fmaxf(fmaxf(red[0], red[1]), fmaxf(red[2], red[3]));
  __syncthreads();

  float lsum = 0.f;
  #pragma unroll
  for (int it = 0; it < 4; ++it) {
    const int i = (it * 256 + tid) * 4;
    #pragma unroll
    for (int j = 0; j < 4; ++j) {
      float v = 0.f;
      if (ua[it * 4 + j] != 0.f) {
        const float e = __expf(t[i + j] - m);
        lsum += e;                    // denominator: plain exp sum
        v = e * ua[it * 4 + j];
      }
      t[i + j] = v;
    }
  }
  #pragma unroll
  for (int off = 32; off > 0; off >>= 1) lsum += __shfl_down(lsum, off);
  if ((tid & 63) == 0) red[tid >> 6] = lsum;
  __syncthreads();
  const float S = red[0] + red[1] + red[2] + red[3];
  const float inv = (S > 0.f) ? 1.0f / S : 0.0f;

  f16* arow = att + (size_t)b * In;
  #pragma unroll
  for (int it = 0; it < 2; ++it) {
    const int i = (it * 256 + tid) * 8;
    f16x8 h;
    #pragma unroll
    for (int j = 0; j < 8; ++j) h[j] = (f16)(t[i + j] * inv);
    *reinterpret_cast<f16x8*>(arow + i) = h;
  }
}

// ---------------------------------------------------------------------------
// MFMA GEMM: 64x64 tile, BK=64, 4 waves (2x2 of 32x32).
// Round-13 changes vs r12 (diagnosed from r12 counters):
//  1. T3-minimum 2-phase double-buffer: STAGE(next) issued BEFORE compute,
//     ONE barrier/iter -> HBM latency of next tile hides under ds_read+MFMA
//     (r12 exposed ~900cy/iter: stage->barrier->compute).
//  2. T2 XOR-swizzle both-sides (rule #21): linear LDS dest, pre-swizzled
//     GLOBAL source slot (s^rgrp), swizzled READ slot (g16^(row&7)).
//     r12's 16-way ds_read conflict (7.86M cycles) -> minimum 8-deep.
//  3. Optional split-K (fp32 partials) to fix uf's 1-block/CU tail.
// LDS content invariant: LDS[row][slot] = G[row][slot ^ (row&7)] (16B slots).
// Fragment lane-maps identical to HW-verified rounds 4-12.
// ---------------------------------------------------------------------------
struct GemmDesc {
  const f16* A;        // 2048 x K row-major
  const f16* Wt;       // N x K row-major (W transposed)
  const float* bias;
  f16* C;              // fp16 out (P==nullptr)
  float* P;            // fp32 partials [S][2048][N] (split-K)
  int K, Kc, ldc, nTilesN, relu;
};

__global__ __launch_bounds__(256, 2) void k_mgemm(GemmDesc dA, GemmDesc dB, int bSplit) {
  __shared__ __align__(16) f16 As[2][64 * 64];
  __shared__ __align__(16) f16 Bs[2][64 * 64];

  const bool second = ((int)blockIdx.x >= bSplit);
  const GemmDesc d = second ? dB : dA;
  const int local = second ? (int)blockIdx.x - bSplit : (int)blockIdx.x;

  const int bm = (local & 31) * 64;            // 32 m-tiles (M=2048)
  const int rest = local >> 5;
  const int bn = (rest % d.nTilesN) * 64;
  const int ks = rest / d.nTilesN;
  const size_t kBeg = (size_t)ks * d.Kc;

  const int tid  = threadIdx.x;
  const int lane = tid & 63;
  const int wave = tid >> 6;
  const int wrow = (wave >> 1) * 32;
  const int wcol = (wave & 1) * 32;
  const int lrow = lane & 15;

  // ---- staging map: wave owns chunks c0,c0+1 (8 rows each) of A and B ----
  const int c0    = wave * 2;
  const int rgrp  = lane >> 3;                 // row within chunk (0..7)
  const int sslot = lane & 7;                  // dest 16B slot (HW-fixed)
  const int scol  = ((sslot ^ rgrp) * 8);      // SWIZZLED source halfs

  const f16* gA0 = d.A  + (size_t)(bm + c0 * 8 + rgrp) * d.K + kBeg + scol;
  const f16* gA1 = d.A  + (size_t)(bm + c0 * 8 + 8 + rgrp) * d.K + kBeg + scol;
  const f16* gB0 = d.Wt + (size_t)(bn + c0 * 8 + rgrp) * d.K + kBeg + scol;
  const f16* gB1 = d.Wt + (size_t)(bn + c0 * 8 + 8 + rgrp) * d.K + kBeg + scol;
  const int lA0 = (c0 + 0) * 512;              // wave-uniform LDS half-offsets
  const int lA1 = (c0 + 1) * 512;

  #define STAGE(buf, k0)                                   \
    gld16(gA0 + (k0), &As[buf][lA0]);                      \
    gld16(gA1 + (k0), &As[buf][lA1]);                      \
    gld16(gB0 + (k0), &Bs[buf][lA0]);                      \
    gld16(gB1 + (k0), &Bs[buf][lA1]);

  // ---- fragment-read swizzle: slot = g16 ^ (row&7); row&7 == lrow&7 here ----
  const int r7 = lrow & 7;
  const int sw0 = ((0 * 4 + (lane >> 4)) ^ r7) * 8;   // kss=0 halfs offset
  const int sw1 = ((1 * 4 + (lane >> 4)) ^ r7) * 8;   // kss=1

  f32x4 acc[2][2] = {};

  STAGE(0, 0);
  __syncthreads();                   // buf0 resident
  int cur = 0;
  for (int k0 = 0; k0 < d.Kc; k0 += 64) {
    if (k0 + 64 < d.Kc) { STAGE(cur ^ 1, k0 + 64); }   // async, other buffer

    const f16* A_ = As[cur];
    const f16* B_ = Bs[cur];
    #pragma unroll
    for (int kss = 0; kss < 2; ++kss) {
      const int sw = kss ? sw1 : sw0;
      const f16x8 a0 = *reinterpret_cast<const f16x8*>(&A_[(wrow +  0 + lrow) * 64 + sw]);
      const f16x8 a1 = *reinterpret_cast<const f16x8*>(&A_[(wrow + 16 + lrow) * 64 + sw]);
      const f16x8 b0 = *reinterpret_cast<const f16x8*>(&B_[(wcol +  0 + lrow) * 64 + sw]);
      const f16x8 b1 = *reinterpret_cast<const f16x8*>(&B_[(wcol + 16 + lrow) * 64 + sw]);

      acc[0][0] = __builtin_amdgcn_mfma_f32_16x16x32_f16(a0, b0, acc[0][0], 0, 0, 0);
      acc[0][1] = __builtin_amdgcn_mfma_f32_16x16x32_f16(a0, b1, acc[0][1], 0, 0, 0);
      acc[1][0] = __builtin_amdgcn_mfma_f32_16x16x32_f16(a1, b0, acc[1][0], 0, 0, 0);
      acc[1][1] = __builtin_amdgcn_mfma_f32_16x16x32_f16(a1, b1, acc[1][1], 0, 0, 0);
    }
    __syncthreads();                 // drains next-tile loads (in flight
    cur ^= 1;                        // during compute) + protects LDS reuse
  }
  #undef STAGE

  // epilogue (C/D map: col=lane&15, row=(lane>>4)*4+reg — HW-verified)
  const int orow = (lane >> 4) * 4;
  if (d.P) {
    const int N = d.nTilesN * 64;
    float* pp = d.P + (size_t)ks * ((size_t)2048 * N);
    #pragma unroll
    for (int mf = 0; mf < 2; ++mf)
      #pragma unroll
      for (int nf = 0; nf < 2; ++nf) {
        const int col = bn + wcol + nf * 16 + lrow;
        #pragma unroll
        for (int rr = 0; rr < 4; ++rr) {
          const int row = bm + wrow + mf * 16 + orow + rr;
          pp[(size_t)row * N + col] = acc[mf][nf][rr];
        }
      }
  } else {
    #pragma unroll
    for (int mf = 0; mf < 2; ++mf)
      #pragma unroll
      for (int nf = 0; nf < 2; ++nf) {
        const int col = bn + wcol + nf * 16 + lrow;
        const float bv = d.bias ? d.bias[col] : 0.f;
        #pragma unroll
        for (int rr = 0; rr < 4; ++rr) {
          const int row = bm + wrow + mf * 16 + orow + rr;
          float v = acc[mf][nf][rr] + bv;
          if (d.relu) v = fmaxf(v, 0.f);
          d.C[(size_t)row * d.ldc + col] = (f16)v;
        }
      }
  }
}

// ---------------------------------------------------------------------------
// Sum S fp32 partial planes (+bias+ReLU) -> fp16 (verified round 9).
// ---------------------------------------------------------------------------
__global__ __launch_bounds__(256) void k_reduce(const float* __restrict__ P,
                                                int S, int MN, int N,
                                                const float* __restrict__ bias,
                                                int relu, f16* __restrict__ C,
                                                int ldc) {
  const int idx = (blockIdx.x * 256 + threadIdx.x) * 8;
  float v[8];
  {
    const float4 a0 = *reinterpret_cast<const float4*>(P + idx);
    const float4 a1 = *reinterpret_cast<const float4*>(P + idx + 4);
    v[0] = a0.x; v[1] = a0.y; v[2] = a0.z; v[3] = a0.w;
    v[4] = a1.x; v[5] = a1.y; v[6] = a1.z; v[7] = a1.w;
  }
  for (int s = 1; s < S; ++s) {
    const float* ps = P + (size_t)s * MN + idx;
    const float4 b0 = *reinterpret_cast<const float4*>(ps);
    const float4 b1 = *reinterpret_cast<const float4*>(ps + 4);
    v[0] += b0.x; v[1] += b0.y; v[2] += b0.z; v[3] += b0.w;
    v[4] += b1.x; v[5] += b1.y; v[6] += b1.z; v[7] += b1.w;
  }
  const int row = idx / N;
  const int col = idx % N;
  f16x8 h;
  #pragma unroll
  for (int j = 0; j < 8; ++j) {
    float x = v[j] + (bias ? bias[col + j] : 0.f);
    if (relu) x = fmaxf(x, 0.f);
    h[j] = (f16)x;
  }
  *reinterpret_cast<f16x8*>(C + (size_t)row * ldc + col) = h;
}

// ---------------------------------------------------------------------------
// Fused merge-layer-3 + final projection (verified rounds 10/12).
// ---------------------------------------------------------------------------
__global__ __launch_bounds__(256) void k_tail(const f16* __restrict__ h2,
                                              const f16* __restrict__ t_mw3,
                                              const float* __restrict__ mb3,
                                              const float* __restrict__ mw4,
                                              const float* __restrict__ mb4,
                                              float* __restrict__ out) {
  __shared__ f16 rows[4][512];
  __shared__ float red[4][4];
  const int tid = threadIdx.x;
  const int r0 = blockIdx.x * 4;

  *reinterpret_cast<f16x8*>(&rows[tid >> 6][(tid & 63) * 8]) =
      *reinterpret_cast<const f16x8*>(&h2[(size_t)(r0 + (tid >> 6)) * 512 + (tid & 63) * 8]);
  __syncthreads();

  const int j = tid;
  float acc[4] = {};
  for (int k = 0; k < 512; k += 8) {
    const f16x8 w = *reinterpret_cast<const f16x8*>(&t_mw3[(size_t)j * 512 + k]);
    #pragma unroll
    for (int e = 0; e < 8; ++e) {
      const float wf = (float)w[e];
      #pragma unroll
      for (int r = 0; r < 4; ++r)
        acc[r] = fmaf(wf, (float)rows[r][k + e], acc[r]);
    }
  }
  const float b3 = mb3[j];
  const float m4 = mw4[j];
  const int lane = tid & 63;
  const int wid  = tid >> 6;
  #pragma unroll
  for (int r = 0; r < 4; ++r) {
    float v = fmaxf(acc[r] + b3, 0.f) * m4;
    #pragma unroll
    for (int off = 32; off > 0; off >>= 1) v += __shfl_down(v, off);
    if (lane == 0) red[r][wid] = v;
  }
  __syncthreads();
  if (tid < 4)
    out[r0 + tid] = red[tid][0] + red[tid][1] + red[tid][2] + red[tid][3] + mb4[0];
}

// ---------------------------------------------------------------------------
extern "C" void kernel_launch(void* const* d_in, const int* in_sizes, int n_in,
                              void* d_out, int out_size, void* d_ws, size_t ws_size,
                              hipStream_t stream) {
  const float* cand  = (const float*)d_in[0];
  const float* rated = (const float*)d_in[1];
  const float* um    = (const float*)d_in[2];
  const float* att_w = (const float*)d_in[3];
  const float* iw1 = (const float*)d_in[5];
  const float* ib1 = (const float*)d_in[6];
  const float* iw2 = (const float*)d_in[7];
  const float* ib2 = (const float*)d_in[8];
  const float* uw1 = (const float*)d_in[9];
  const float* ub1 = (const float*)d_in[10];
  const float* uw2 = (const float*)d_in[11];
  const float* ub2 = (const float*)d_in[12];
  const float* mw1 = (const float*)d_in[13];
  const float* mb1 = (const float*)d_in[14];
  const float* mw2 = (const float*)d_in[15];
  const float* mb2 = (const float*)d_in[16];
  const float* mw3 = (const float*)d_in[17];
  const float* mb3 = (const float*)d_in[18];
  const float* mw4 = (const float*)d_in[19];
  const float* mb4 = (const float*)d_in[20];
  float* out = (float*)d_out;

  // ---- workspace layout (fp16 element units); ~65 MB ----
  f16*   hws = (f16*)d_ws;
  float* rs  = (float*)d_ws;            // 4096 fp32 = 8192 half-slots
  size_t off = 8192;
  auto take = [&](size_t n) { f16* p = hws + off; off += n; return p; };
  f16* t_iw1   = take(512 * 1024);
  f16* t_iw2   = take(1024 * 512);
  f16* t_uw1   = take(512 * 2048);
  f16* t_uw2   = take(2048 * 1024);
  f16* t_mw1   = take(1536 * 1024);
  f16* t_mw2   = take(1024 * 512);
  f16* t_mw3   = take(512 * 256);
  f16* t_rated = take(512 * 4096);
  f16* cand_h  = take(2048 * 512);
  f16* uf_h    = take(2048 * 512);
  f16* att_d   = take(2048 * 4096);     // 16 MB; h_u1 aliases after G2
  f16* h_i1    = take(2048 * 1024);     // h_m1 aliases after G4
  f16* Xc      = take(2048 * 1536);
  float* Pbuf  = (float*)take(4 * 2048 * 512 * 2);   // 16 MB fp32 partials
  f16* h_u1 = att_d;                    // att_d dead after G1
  f16* h_m1 = h_i1;                     // h_i1 dead after G2
  f16* h_m2 = uf_h;                     // uf_h dead after G2

  dim3 blk(256);

  // 1. attention logits
  k_rs<<<dim3(In / 4), blk, 0, stream>>>(rated, att_w, rs);

  // 2. merged: dense attention matrix + all weight transposes + cand cast
  PrepPack pk = {{
      { rated, t_rated, 4096,  512, (512/32)*(4096/32), 0 },
      { iw1,   t_iw1,    512, 1024, (1024/32)*(512/32), 0 },
      { iw2,   t_iw2,   1024,  512, (512/32)*(1024/32), 0 },
      { uw1,   t_uw1,    512, 2048, (2048/32)*(512/32), 0 },
      { uw2,   t_uw2,   2048, 1024, (1024/32)*(2048/32), 0 },
      { mw1,   t_mw1,   1536, 1024, (1024/32)*(1536/32), 0 },
      { mw2,   t_mw2,   1024,  512, (512/32)*(1024/32), 0 },
      { mw3,   t_mw3,    512,  256, (256/32)*(512/32), 0 },
      { cand,  cand_h,     0,    0, (Bn * Dn) / 1024, 1 },
  }};
  int prepGrid = 0;
  for (int q = 0; q < 9; ++q) prepGrid += pk.d[q].nt;
  k_attprep<<<dim3(Bn + prepGrid), blk, 0, stream>>>(um, rs, att_d, pk);

  // GEMM descriptors (64x64 tiles; 32 m-tiles)
  GemmDesc dUF = { att_d,  t_rated, nullptr, nullptr,  Pbuf,   4096, 1024,  512,  8, 0 };
  GemmDesc dI1 = { cand_h, t_iw1,   ib1,     h_i1,     nullptr, 512,  512, 1024, 16, 1 };
  GemmDesc dU1 = { uf_h,   t_uw1,   ub1,     h_u1,     nullptr, 512,  512, 2048, 32, 1 };
  GemmDesc dI2 = { h_i1,   t_iw2,   ib2,     Xc,       nullptr, 1024, 1024, 1536, 8, 1 };
  GemmDesc dU2 = { h_u1,   t_uw2,   ub2,     Xc + 512, nullptr, 2048, 2048, 1536, 16, 1 };
  GemmDesc dM1 = { Xc,     t_mw1,   mb1,     h_m1,     nullptr, 1536, 1536, 1024, 16, 1 };
  GemmDesc dM2 = { h_m1,   t_mw2,   mb2,     h_m2,     nullptr, 1024, 1024,  512,  8, 1 };

  // G1: uf split-K x4 (1024 wg, 16 iters/blk) + item layer 1 (512 wg, 8 iters)
  k_mgemm<<<dim3(1536), blk, 0, stream>>>(dUF, dI1, 1024);
  k_reduce<<<dim3(512), blk, 0, stream>>>(Pbuf, 4, 2048 * 512, 512, nullptr, 0, uf_h, 512);

  // G2: user layer 1 (1024 wg) + item layer 2 (256 wg)
  k_mgemm<<<dim3(1280), blk, 0, stream>>>(dU1, dI2, 1024);
  // G3: user layer 2 (512 wg)
  k_mgemm<<<dim3(512), blk, 0, stream>>>(dU2, dU2, 512);
  // G4: merge layer 1 (512 wg)
  k_mgemm<<<dim3(512), blk, 0, stream>>>(dM1, dM1, 512);
  // G5: merge layer 2 (256 wg)
  k_mgemm<<<dim3(256), blk, 0, stream>>>(dM2, dM2, 256);

  // fused merge layer 3 + final projection
  k_tail<<<dim3(Bn / 4), blk, 0, stream>>>(h_m2, t_mw3, mb3, mw4, mb4, out);
}